// Round 12
// baseline (240.689 us; speedup 1.0000x reference)
//
#include <hip/hip_runtime.h>

#define HID 128
#define NNODE 10000
#define KN 16
#define ROWS 80000    // BATCH * NNODE
#define NTILES 2500   // ROWS / 32
#define ACHUNK 313    // ceil(NNODE/32)
#define AUGRID (8 * ACHUNK)   // 2504 fused blocks

typedef __attribute__((ext_vector_type(8))) short short8;   // 8 bf16 (4 VGPRs)
typedef __attribute__((ext_vector_type(4))) float f32x4;
typedef __attribute__((ext_vector_type(2))) float f32x2;
typedef __attribute__((ext_vector_type(4))) unsigned int u32x4;
typedef __attribute__((ext_vector_type(2))) unsigned int u32x2;

__device__ __forceinline__ unsigned short f2b(float f) {
    unsigned u = __float_as_uint(f);
    u += 0x7FFFu + ((u >> 16) & 1u);       // round-to-nearest-even
    return (unsigned short)(u >> 16);
}

// Weight transpose+convert: W1t[128][64], W2t[128][128], Wu1t[128][256], Wu2t[128][256].
__global__ __launch_bounds__(256) void wconv_all(
    const float* __restrict__ W1, const float* __restrict__ W2,
    const float* __restrict__ Wu1, const float* __restrict__ Wu2,
    unsigned short* __restrict__ W1t, unsigned short* __restrict__ W2t,
    unsigned short* __restrict__ Wu1t, unsigned short* __restrict__ Wu2t) {
    int idx = blockIdx.x * 256 + threadIdx.x;   // < 90112
    const float* W; unsigned short* Wt; int K; int off;
    if (idx < 8192)       { W = W1;  Wt = W1t;  K = 64;  off = idx; }
    else if (idx < 24576) { W = W2;  Wt = W2t;  K = 128; off = idx - 8192; }
    else if (idx < 57344) { W = Wu1; Wt = Wu1t; K = 256; off = idx - 24576; }
    else                  { W = Wu2; Wt = Wu2t; K = 256; off = idx - 57344; }
    int n = off & 127, k = off >> 7;
    Wt[n * K + k] = f2b(W[off]);
}

// Embed: Y[r][:] = relu(X[r][:]@W + b); transposed-operand MFMA, persistent
// W-frags, grid-stride, 2-deep x pipeline. Tiles >= NTILES -> (A1,Y1).
template<int K, bool AF32>
__global__ __launch_bounds__(512) void embed2(
    const void* __restrict__ A0, const void* __restrict__ A1,
    const unsigned short* __restrict__ Wt, const float* __restrict__ bias,
    unsigned short* __restrict__ Y0, unsigned short* __restrict__ Y1, int tot) {
    const int t = threadIdx.x, w = t >> 6, lane = t & 63;
    const int lrow = lane & 15, lk = lane >> 4;
    const int rs = w & 1, ng = w >> 1;
    const int col0 = ng * 32;

    short8 wf[2][K / 32];
    f32x4 bv[2];
#pragma unroll
    for (int p = 0; p < 2; ++p) {
        bv[p] = *(const f32x4*)(bias + col0 + p * 16 + lk * 4);
#pragma unroll
        for (int kt = 0; kt < K / 32; ++kt)
            wf[p][kt] = *(const short8*)(Wt + (col0 + p * 16 + lrow) * K + kt * 32 + lk * 8);
    }

    int T = blockIdx.x;
    if (T >= tot) return;

    auto loadx = [&](int TT, short8* xf) {
        const int half = TT >= NTILES;
        const void* A = half ? A1 : A0;
        const int row = (TT - half * NTILES) * 32 + rs * 16 + lrow;
        if constexpr (AF32) {
            const float* X = (const float*)A + (size_t)row * K;
#pragma unroll
            for (int kt = 0; kt < K / 32; ++kt) {
                f32x4 f0 = *(const f32x4*)(X + kt * 32 + lk * 8);
                f32x4 f1 = *(const f32x4*)(X + kt * 32 + lk * 8 + 4);
                short8 v;
#pragma unroll
                for (int e = 0; e < 4; ++e) { v[e] = (short)f2b(f0[e]); v[4 + e] = (short)f2b(f1[e]); }
                xf[kt] = v;
            }
        } else {
            const unsigned short* X = (const unsigned short*)A + (size_t)row * K;
#pragma unroll
            for (int kt = 0; kt < K / 32; ++kt)
                xf[kt] = *(const short8*)(X + kt * 32 + lk * 8);
        }
    };

    short8 xf[K / 32], xn[K / 32];
    loadx(T, xf);
    for (;;) {
        const int Tn = T + gridDim.x;
        const bool more = Tn < tot;
        if (more) loadx(Tn, xn);

        const int half = T >= NTILES;
        unsigned short* Y = half ? Y1 : Y0;
        const int row = (T - half * NTILES) * 32 + rs * 16 + lrow;
#pragma unroll
        for (int p = 0; p < 2; ++p) {
            f32x4 acc = {0.f, 0.f, 0.f, 0.f};
#pragma unroll
            for (int kt = 0; kt < K / 32; ++kt)
                acc = __builtin_amdgcn_mfma_f32_16x16x32_bf16(wf[p][kt], xf[kt], acc, 0, 0, 0);
            float v0 = acc[0] + bv[p][0]; v0 = v0 > 0.f ? v0 : 0.f;
            float v1 = acc[1] + bv[p][1]; v1 = v1 > 0.f ? v1 : 0.f;
            float v2 = acc[2] + bv[p][2]; v2 = v2 > 0.f ? v2 : 0.f;
            float v3 = acc[3] + bv[p][3]; v3 = v3 > 0.f ? v3 : 0.f;
            u32x2 ov = {(unsigned)f2b(v0) | ((unsigned)f2b(v1) << 16),
                        (unsigned)f2b(v2) | ((unsigned)f2b(v3) << 16)};
            *(u32x2*)(Y + (size_t)row * HID + col0 + p * 16 + lk * 4) = ov;
        }
        if (!more) break;
#pragma unroll
        for (int kt = 0; kt < K / 32; ++kt) xf[kt] = xn[kt];
        T = Tn;
    }
}

// Fused gather+update. Block = 32 rows of one batch b (bid&7 -> XCD affinity).
// Phase A: 16 thr/row x 16B gather, dual tensor, f32 accumulate, bf16 into
//          XOR-swizzled LDS tile At[32][128].
// Phase B: Y = relu([G|H]@Wut^T + bu); G-frags from LDS, H-frags from global.
__global__ __launch_bounds__(512) void k_aggr_update(
    const unsigned short* __restrict__ SE, const unsigned short* __restrict__ IE,
    const int* __restrict__ sidx, const int* __restrict__ iidx,
    const unsigned short* __restrict__ Wut, const float* __restrict__ bu,
    float* __restrict__ Yf, unsigned short* __restrict__ Yb, int writeb) {
    __shared__ int sh[32][33];                               // padded, conflict-free
    __shared__ __align__(16) unsigned short At[32 * 128];    // 8 KB swizzled
    const int t = threadIdx.x;
    const int b = blockIdx.x & 7;
    const int n0 = (blockIdx.x >> 3) * 32;
    const size_t gbase = (size_t)b * NNODE * HID;

    // ---- stage indices: e -> row r=e>>5, slot k=e&31 (0-15 sidx, 16-31 iidx)
#pragma unroll
    for (int q = 0; q < 2; ++q) {
        const int e = t + q * 512;
        const int r = e >> 5, k = e & 31;
        int nr = n0 + r; if (nr > NNODE - 1) nr = NNODE - 1;
        sh[r][k] = (k < KN) ? sidx[nr * KN + k] : iidx[nr * KN + (k - KN)];
    }
    __syncthreads();

    {   // ---- Phase A: gather + aggregate, 16 thr/row x 16B (full 128 cols)
        const int r = t >> 4, p = t & 15;
        const int col0 = p * 8;
        const size_t base = gbase + col0;

        f32x2 acc[4];
#pragma unroll
        for (int w = 0; w < 4; ++w) acc[w] = (f32x2){0.f, 0.f};

#pragma unroll
        for (int q = 0; q < 4; ++q) {
            const unsigned short* P = (q < 2) ? SE : IE;
            u32x4 vals[8];
#pragma unroll
            for (int j = 0; j < 8; ++j)
                vals[j] = *(const u32x4*)(P + base + (size_t)sh[r][q * 8 + j] * HID);
#pragma unroll
            for (int j = 0; j < 8; ++j)
#pragma unroll
                for (int w = 0; w < 4; ++w) {
                    const unsigned u = vals[j][w];
                    acc[w] += (f32x2){__uint_as_float(u << 16),
                                      __uint_as_float(u & 0xffff0000u)};
                }
        }
        short8 ov;
#pragma unroll
        for (int w = 0; w < 4; ++w) {
            ov[2 * w]     = (short)f2b(acc[w].x);
            ov[2 * w + 1] = (short)f2b(acc[w].y);
        }
        *(short8*)((char*)At + r * 256 + ((col0 * 2) ^ ((r & 7) << 4))) = ov;
    }
    __syncthreads();

    // ---- Phase B: [32 x 256] @ Wut^T (transposed-operand, W as A)
    const int w = t >> 6, lane = t & 63;
    const int lrow = lane & 15, lk = lane >> 4;
    const int rs = w & 1, ng = w >> 1;
    const int col0 = ng * 32;
    const int rowl = rs * 16 + lrow;
    const int n = n0 + rowl;

    short8 wf[2][8];
    f32x4 bv[2];
#pragma unroll
    for (int p = 0; p < 2; ++p) {
        bv[p] = *(const f32x4*)(bu + col0 + p * 16 + lk * 4);
#pragma unroll
        for (int kt = 0; kt < 8; ++kt)
            wf[p][kt] = *(const short8*)(Wut + (col0 + p * 16 + lrow) * 256 + kt * 32 + lk * 8);
    }

    short8 xf[8];
#pragma unroll
    for (int kt = 0; kt < 4; ++kt)
        xf[kt] = *(const short8*)((const char*)At + rowl * 256 +
                                  ((kt * 64 + lk * 16) ^ ((rowl & 7) << 4)));
    {
        const int nh = n < NNODE ? n : NNODE - 1;
        const unsigned short* Hrow = IE + gbase + (size_t)nh * HID;
#pragma unroll
        for (int kt = 0; kt < 4; ++kt)
            xf[4 + kt] = *(const short8*)(Hrow + kt * 32 + lk * 8);
    }

    const bool ok = n < NNODE;
    const size_t orow = gbase + (size_t)n * HID;
#pragma unroll
    for (int p = 0; p < 2; ++p) {
        f32x4 acc = {0.f, 0.f, 0.f, 0.f};
#pragma unroll
        for (int kt = 0; kt < 8; ++kt)
            acc = __builtin_amdgcn_mfma_f32_16x16x32_bf16(wf[p][kt], xf[kt], acc, 0, 0, 0);
        f32x4 o;
#pragma unroll
        for (int j = 0; j < 4; ++j) {
            float v = acc[j] + bv[p][j];
            o[j] = v > 0.f ? v : 0.f;
        }
        if (ok) {
            *(f32x4*)(Yf + orow + col0 + p * 16 + lk * 4) = o;
            if (writeb) {
                u32x2 ov = {(unsigned)f2b(o[0]) | ((unsigned)f2b(o[1]) << 16),
                            (unsigned)f2b(o[2]) | ((unsigned)f2b(o[3]) << 16)};
                *(u32x2*)(Yb + orow + col0 + p * 16 + lk * 4) = ov;
            }
        }
    }
}

extern "C" void kernel_launch(void* const* d_in, const int* in_sizes, int n_in,
                              void* d_out, int out_size, void* d_ws, size_t ws_size,
                              hipStream_t stream) {
    const float* state    = (const float*)d_in[0];
    const float* internal = (const float*)d_in[1];
    const int*   sidx     = (const int*)d_in[2];
    const int*   iidx     = (const int*)d_in[3];
    const float* W1  = (const float*)d_in[4];
    const float* b1  = (const float*)d_in[5];
    const float* W2  = (const float*)d_in[6];
    const float* b2  = (const float*)d_in[7];
    const float* Wu1 = (const float*)d_in[8];
    const float* bu1 = (const float*)d_in[9];
    const float* Wu2 = (const float*)d_in[10];
    const float* bu2 = (const float*)d_in[11];

    float* hu1 = (float*)d_out;
    float* hu2 = hu1 + (size_t)ROWS * HID;

    unsigned short* W1t  = (unsigned short*)d_ws;          // 8192
    unsigned short* W2t  = W1t + 8192;                     // 16384
    unsigned short* Wu1t = W2t + 16384;                    // 32768
    unsigned short* Wu2t = Wu1t + 32768;                   // 32768
    unsigned short* buf0 = Wu2t + 32768;                   // weights total 90112
    unsigned short* buf1 = buf0 + (size_t)ROWS * HID;      // 10.24M elems each
    unsigned short* buf2 = buf1 + (size_t)ROWS * HID;
    unsigned short* buf3 = buf2 + (size_t)ROWS * HID;

    const size_t need_big = ((size_t)90112 + 4 * (size_t)ROWS * HID) * 2;
    const bool big = ws_size >= need_big;

    dim3 b256(256), b512(512);

    wconv_all<<<352, b256, 0, stream>>>(W1, W2, Wu1, Wu2, W1t, W2t, Wu1t, Wu2t);

    // K1: layer-1 embeddings SE1->buf0, IE1->buf1
    embed2<64, true><<<1250, b512, 0, stream>>>(state, internal, W1t, b1,
                                                buf0, buf1, 2 * NTILES);

    // K2: fused aggr1+update1: hu1 -> d_out (f32), hu1b -> buf2 (bf16)
    k_aggr_update<<<AUGRID, b512, 0, stream>>>(buf0, buf1, sidx, iidx,
                                               Wu1t, bu1, hu1, buf2, 1);

    if (big) {
        // K3: se2: buf0 -> buf3 ; ie2: buf2 -> buf1 (IE1 dead) — one launch
        embed2<128, false><<<1250, b512, 0, stream>>>(buf0, buf2, W2t, b2,
                                                      buf3, buf1, 2 * NTILES);
        // K4: fused aggr2+update2: hu2 -> d_out
        k_aggr_update<<<AUGRID, b512, 0, stream>>>(buf3, buf1, sidx, iidx,
                                                   Wu2t, bu2, hu2, nullptr, 0);
    } else {
        // 3-buffer fallback: sequential embeds
        // se2: buf0 -> buf1 (IE1 dead)
        embed2<128, false><<<1250, b512, 0, stream>>>(buf0, nullptr, W2t, b2,
                                                      buf1, nullptr, NTILES);
        // ie2: buf2 -> buf0 (SE1 dead)
        embed2<128, false><<<1250, b512, 0, stream>>>(buf2, nullptr, W2t, b2,
                                                      buf0, nullptr, NTILES);
        // fused aggr2+update2 (SE=se2=buf1, IE=ie2=buf0)
        k_aggr_update<<<AUGRID, b512, 0, stream>>>(buf1, buf0, sidx, iidx,
                                                   Wu2t, bu2, hu2, nullptr, 0);
    }
}